// Round 1
// baseline (306.293 us; speedup 1.0000x reference)
//
#include <hip/hip_runtime.h>
#include <stdint.h>

#define NLAYERS 3
#define NQ 8
#define DIM 256          // 2^NQ
#define KDIM 512         // 2*DIM (real+imag)
#define BM 64            // batch rows per block
#define LDSTR 72         // LDS row stride in bf16 (64 + 8 pad -> 2-way-only bank conflicts)

typedef float  f32x4  __attribute__((ext_vector_type(4)));
typedef __bf16 bf16x8 __attribute__((ext_vector_type(8)));

__device__ __forceinline__ unsigned short f2bf(float f){
    union { float f; uint32_t u; } v; v.f = f;
    uint32_t u = v.u;
    u += 0x7fffu + ((u >> 16) & 1u);   // round-to-nearest-even
    return (unsigned short)(u >> 16);
}

__device__ __forceinline__ float2 cmul(float2 a, float2 b){
    return make_float2(a.x*b.x - a.y*b.y, a.x*b.y + a.y*b.x);
}

// ---------------------------------------------------------------------------
// Kernel 1: build G (256x512 bf16, row-major [n][k]) from params.
// Block j simulates the circuit on basis state e_j (column j of U) in LDS.
// Reference conventions: wire q <-> bit (7-q); output half = indices < 128.
// G = [[Wre, -Wim],[Wim, Wre]], W = U[0:128, :].
// ---------------------------------------------------------------------------
__global__ __launch_bounds__(256) void build_g_kernel(const float* __restrict__ params,
                                                      unsigned short* __restrict__ G){
    __shared__ float2 st[2][DIM];
    const int j = blockIdx.x;
    const int i = threadIdx.x;
    int cur = 0;
    st[0][i] = make_float2(i == j ? 1.0f : 0.0f, 0.0f);
    __syncthreads();

    for (int l = 0; l < NLAYERS; ++l){
        // single-qubit rotations U = RZ * RY * RX
        for (int q = 0; q < NQ; ++q){
            const float* pp = params + (l*NQ + q)*3;
            float hx = 0.5f*pp[0], hy = 0.5f*pp[1], hz = 0.5f*pp[2];
            float cx = cosf(hx), sx = sinf(hx);
            float cy = cosf(hy), sy = sinf(hy);
            float cz = cosf(hz), sz = sinf(hz);
            float2 ezm = make_float2(cz, -sz), ezp = make_float2(cz, sz);
            // M = RY*RX
            float2 m00 = make_float2( cy*cx,  sy*sx);
            float2 m01 = make_float2(-sy*cx, -cy*sx);
            float2 m10 = make_float2( sy*cx, -cy*sx);
            float2 m11 = make_float2( cy*cx, -sy*sx);
            float2 U0a = cmul(ezm, m00), U0b = cmul(ezm, m01);
            float2 U1a = cmul(ezp, m10), U1b = cmul(ezp, m11);
            int p  = 7 - q;                 // bit index of this wire
            int bs = (i >> p) & 1;
            int i0 = i & ~(1 << p), i1 = i | (1 << p);
            float2 a0 = st[cur][i0], a1 = st[cur][i1];
            float2 ua = bs ? U1a : U0a;
            float2 ub = bs ? U1b : U0b;
            float2 r;
            r.x = ua.x*a0.x - ua.y*a0.y + ub.x*a1.x - ub.y*a1.y;
            r.y = ua.x*a0.y + ua.y*a0.x + ub.x*a1.y + ub.y*a1.x;
            st[cur ^ 1][i] = r;
            cur ^= 1;
            __syncthreads();
        }
        // CNOT ring: ctrl q, tgt (q+1)%8
        for (int q = 0; q < NQ; ++q){
            int c  = 7 - q;
            int tb = 7 - ((q + 1) & 7);
            int src = ((i >> c) & 1) ? (i ^ (1 << tb)) : i;
            float2 r = st[cur][src];
            st[cur ^ 1][i] = r;
            cur ^= 1;
            __syncthreads();
        }
    }

    // write column j (and j+256) of G
    const int m = i & 127;
    float2 a = st[cur][m];
    unsigned short lo, hi;
    if (i < 128){ lo = f2bf(a.x); hi = f2bf(-a.y); }   // Wre | -Wim
    else        { lo = f2bf(a.y); hi = f2bf( a.x); }   // Wim |  Wre
    G[(size_t)i*KDIM + j]        = lo;
    G[(size_t)i*KDIM + j + DIM]  = hi;
}

// ---------------------------------------------------------------------------
// Kernel 2: out[m] = || G * [sr_m ; si_m] ||^2
// Fused GEMM (M=BATCH, N=256, K=512, bf16 MFMA 16x16x32) + squared-norm epilogue.
// Block: 256 threads (4 waves), BM=64 rows, full N=256, K-loop of 8x BK=64.
// Wave w owns N-range [w*64, w*64+64). No cross-block reduction needed.
// ---------------------------------------------------------------------------
__global__ __launch_bounds__(256, 3) void qform_kernel(const float* __restrict__ sr,
                                                       const float* __restrict__ si,
                                                       const unsigned short* __restrict__ G,
                                                       float* __restrict__ out){
    __shared__ unsigned short As[BM  * LDSTR];   //  9216 B
    __shared__ unsigned short Bs[DIM * LDSTR];   // 36864 B
    __shared__ float red[4 * BM];                //  1024 B

    const int tid  = threadIdx.x;
    const int lane = tid & 63;
    const int w    = tid >> 6;        // wave 0..3
    const int l15  = lane & 15;
    const int quad = lane >> 4;       // 0..3
    const size_t mbase = (size_t)blockIdx.x * BM;

    const int arow = tid >> 2;        // 0..63
    const int aseg = tid & 3;         // 0..3 (16-element segment)

    f32x4 acc[4][4];
    const f32x4 vzero = {0.0f, 0.0f, 0.0f, 0.0f};
    #pragma unroll
    for (int ii = 0; ii < 4; ++ii)
        #pragma unroll
        for (int jj = 0; jj < 4; ++jj)
            acc[ii][jj] = vzero;

    for (int kc = 0; kc < 8; ++kc){
        __syncthreads();
        // ---- stage A: 64 rows x 64 k of Z (fp32 -> bf16). k<256: sr, else si.
        {
            const float* ga = ((kc < 4) ? sr : si)
                            + (mbase + arow)*(size_t)DIM + ((kc & 3)*64 + aseg*16);
            float4 f0 = ((const float4*)ga)[0];
            float4 f1 = ((const float4*)ga)[1];
            float4 f2 = ((const float4*)ga)[2];
            float4 f3 = ((const float4*)ga)[3];
            uint32_t pk[8];
            pk[0] = f2bf(f0.x) | ((uint32_t)f2bf(f0.y) << 16);
            pk[1] = f2bf(f0.z) | ((uint32_t)f2bf(f0.w) << 16);
            pk[2] = f2bf(f1.x) | ((uint32_t)f2bf(f1.y) << 16);
            pk[3] = f2bf(f1.z) | ((uint32_t)f2bf(f1.w) << 16);
            pk[4] = f2bf(f2.x) | ((uint32_t)f2bf(f2.y) << 16);
            pk[5] = f2bf(f2.z) | ((uint32_t)f2bf(f2.w) << 16);
            pk[6] = f2bf(f3.x) | ((uint32_t)f2bf(f3.y) << 16);
            pk[7] = f2bf(f3.z) | ((uint32_t)f2bf(f3.w) << 16);
            uint4* da = (uint4*)&As[arow*LDSTR + aseg*16];
            da[0] = make_uint4(pk[0], pk[1], pk[2], pk[3]);
            da[1] = make_uint4(pk[4], pk[5], pk[6], pk[7]);
        }
        // ---- stage B: 256 rows x 64 k of G (bf16 copy, L2-resident)
        #pragma unroll
        for (int pblk = 0; pblk < 4; ++pblk){
            int row = pblk*64 + arow;
            const uint4* gb = (const uint4*)(G + (size_t)row*KDIM + kc*64 + aseg*16);
            uint4 b0 = gb[0], b1 = gb[1];
            uint4* db = (uint4*)&Bs[row*LDSTR + aseg*16];
            db[0] = b0; db[1] = b1;
        }
        __syncthreads();

        // ---- MFMA: 2 ksteps of 32, 4x4 16x16 tiles per wave
        #pragma unroll
        for (int ks = 0; ks < 2; ++ks){
            const int ko = ks*32 + quad*8;
            bf16x8 a[4], b[4];
            #pragma unroll
            for (int ii = 0; ii < 4; ++ii)
                a[ii] = *(const bf16x8*)&As[(ii*16 + l15)*LDSTR + ko];
            #pragma unroll
            for (int jj = 0; jj < 4; ++jj)
                b[jj] = *(const bf16x8*)&Bs[(w*64 + jj*16 + l15)*LDSTR + ko];
            #pragma unroll
            for (int ii = 0; ii < 4; ++ii)
                #pragma unroll
                for (int jj = 0; jj < 4; ++jj)
                    acc[ii][jj] = __builtin_amdgcn_mfma_f32_16x16x32_bf16(
                        a[ii], b[jj], acc[ii][jj], 0, 0, 0);
        }
    }

    // ---- epilogue: out[m] = sum_n Y[m][n]^2
    // C/D layout: n = jj*16 + l15 (col=lane&15), m = ii*16 + quad*4 + r
    float s[4][4];
    #pragma unroll
    for (int ii = 0; ii < 4; ++ii)
        #pragma unroll
        for (int r = 0; r < 4; ++r){
            float t = 0.0f;
            #pragma unroll
            for (int jj = 0; jj < 4; ++jj){ float v = acc[ii][jj][r]; t += v*v; }
            s[ii][r] = t;
        }
    // reduce over the 16 lanes sharing the same quad (n within tiles)
    #pragma unroll
    for (int ii = 0; ii < 4; ++ii)
        #pragma unroll
        for (int r = 0; r < 4; ++r){
            float t = s[ii][r];
            t += __shfl_xor(t, 1);
            t += __shfl_xor(t, 2);
            t += __shfl_xor(t, 4);
            t += __shfl_xor(t, 8);
            s[ii][r] = t;
        }
    if (l15 == 0){
        #pragma unroll
        for (int ii = 0; ii < 4; ++ii)
            #pragma unroll
            for (int r = 0; r < 4; ++r)
                red[w*64 + ii*16 + quad*4 + r] = s[ii][r];
    }
    __syncthreads();
    if (tid < 64){
        float o = red[tid] + red[64 + tid] + red[128 + tid] + red[192 + tid];
        out[mbase + tid] = o;
    }
}

extern "C" void kernel_launch(void* const* d_in, const int* in_sizes, int n_in,
                              void* d_out, int out_size, void* d_ws, size_t ws_size,
                              hipStream_t stream){
    const float* params = (const float*)d_in[0];
    const float* sr     = (const float*)d_in[1];
    const float* si     = (const float*)d_in[2];
    unsigned short* G   = (unsigned short*)d_ws;   // 256*512*2 = 256 KB
    float* out          = (float*)d_out;

    build_g_kernel<<<dim3(DIM), dim3(256), 0, stream>>>(params, G);
    qform_kernel<<<dim3(131072 / BM), dim3(256), 0, stream>>>(sr, si, G, out);
}

// Round 2
// 289.319 us; speedup vs baseline: 1.0587x; 1.0587x over previous
//
#include <hip/hip_runtime.h>
#include <stdint.h>

#define NLAYERS 3
#define NQ 8
#define DIM 256          // 2^NQ
#define KDIM 512         // 2*DIM (real+imag)
#define BM 64            // batch rows per block
#define NBLK (131072 / BM)

typedef float  f32x4  __attribute__((ext_vector_type(4)));
typedef __bf16 bf16x8 __attribute__((ext_vector_type(8)));

__device__ __forceinline__ unsigned short f2bf(float f){
    union { float f; uint32_t u; } v; v.f = f;
    uint32_t u = v.u;
    u += 0x7fffu + ((u >> 16) & 1u);   // round-to-nearest-even
    return (unsigned short)(u >> 16);
}

__device__ __forceinline__ float2 cmul(float2 a, float2 b){
    return make_float2(a.x*b.x - a.y*b.y, a.x*b.y + a.y*b.x);
}

// async 16B global -> LDS (lane dest = uniform base + lane*16)
__device__ __forceinline__ void gload_lds16(void* lds, const void* g){
    __builtin_amdgcn_global_load_lds(
        (const __attribute__((address_space(1))) unsigned int*)g,
        (__attribute__((address_space(3))) unsigned int*)lds,
        16, 0, 0);
}

// ---------------------------------------------------------------------------
// Kernel 1: build G (256x512 bf16, row-major [n][k]) from params.
// Block j simulates the circuit on basis state e_j in LDS.
// Gate matrices precomputed once per block by threads 0..23 (trig hoist).
// The 8 CNOTs of each layer are fused into one composed permutation.
// ---------------------------------------------------------------------------
__global__ __launch_bounds__(256) void build_g_kernel(const float* __restrict__ params,
                                                      unsigned short* __restrict__ G){
    __shared__ float2 st[2][DIM];
    __shared__ float2 gm[NLAYERS*NQ][4];   // U0a,U0b,U1a,U1b per gate
    const int j = blockIdx.x;
    const int i = threadIdx.x;

    if (i < NLAYERS*NQ){
        const float* pp = params + i*3;
        float hx = 0.5f*pp[0], hy = 0.5f*pp[1], hz = 0.5f*pp[2];
        float cx = cosf(hx), sx = sinf(hx);
        float cy = cosf(hy), sy = sinf(hy);
        float cz = cosf(hz), sz = sinf(hz);
        float2 ezm = make_float2(cz, -sz), ezp = make_float2(cz, sz);
        float2 m00 = make_float2( cy*cx,  sy*sx);
        float2 m01 = make_float2(-sy*cx, -cy*sx);
        float2 m10 = make_float2( sy*cx, -cy*sx);
        float2 m11 = make_float2( cy*cx, -sy*sx);
        gm[i][0] = cmul(ezm, m00);
        gm[i][1] = cmul(ezm, m01);
        gm[i][2] = cmul(ezp, m10);
        gm[i][3] = cmul(ezp, m11);
    }

    // composed CNOT-ring permutation (params-independent, same all layers)
    int psrc = i;
    #pragma unroll
    for (int q = NQ-1; q >= 0; --q){
        int c  = 7 - q;
        int tb = 7 - ((q + 1) & 7);
        psrc = ((psrc >> c) & 1) ? (psrc ^ (1 << tb)) : psrc;
    }

    int cur = 0;
    st[0][i] = make_float2(i == j ? 1.0f : 0.0f, 0.0f);
    __syncthreads();

    for (int l = 0; l < NLAYERS; ++l){
        for (int q = 0; q < NQ; ++q){
            float2 U0a = gm[l*NQ+q][0], U0b = gm[l*NQ+q][1];
            float2 U1a = gm[l*NQ+q][2], U1b = gm[l*NQ+q][3];
            int p  = 7 - q;
            int bs = (i >> p) & 1;
            int i0 = i & ~(1 << p), i1 = i | (1 << p);
            float2 a0 = st[cur][i0], a1 = st[cur][i1];
            float2 ua = bs ? U1a : U0a;
            float2 ub = bs ? U1b : U0b;
            float2 r;
            r.x = ua.x*a0.x - ua.y*a0.y + ub.x*a1.x - ub.y*a1.y;
            r.y = ua.x*a0.y + ua.y*a0.x + ub.x*a1.y + ub.y*a1.x;
            st[cur ^ 1][i] = r;
            cur ^= 1;
            __syncthreads();
        }
        // fused CNOT ring
        float2 r = st[cur][psrc];
        st[cur ^ 1][i] = r;
        cur ^= 1;
        __syncthreads();
    }

    const int m = i & 127;
    float2 a = st[cur][m];
    unsigned short lo, hi;
    if (i < 128){ lo = f2bf(a.x); hi = f2bf(-a.y); }   // Wre | -Wim
    else        { lo = f2bf(a.y); hi = f2bf( a.x); }   // Wim |  Wre
    G[(size_t)i*KDIM + j]        = lo;
    G[(size_t)i*KDIM + j + DIM]  = hi;
}

// ---------------------------------------------------------------------------
// Kernel 2: out[m] = || G * [sr_m ; si_m] ||^2
// M=131072, N=256, K=512, mfma 16x16x32 bf16.
// Staging via global_load_lds (width 16): A as raw fp32 (64x64, 16 KB),
// B as bf16 (256x64, 32 KB). XOR-granule-swizzled LDS layouts (DMA cannot
// pad); A converted fp32->bf16 on the LDS->reg path with v_perm truncation.
// 49 KB LDS -> 3 blocks/CU.
// ---------------------------------------------------------------------------
__global__ __launch_bounds__(256, 3) void qform_kernel(const float* __restrict__ sr,
                                                       const float* __restrict__ si,
                                                       const unsigned short* __restrict__ G,
                                                       float* __restrict__ out){
    __shared__ float          As[BM * 64];       // 16 KB, row = 64 fp32 = 16 granules, swizzled
    __shared__ unsigned short Bs[DIM * 64];      // 32 KB, row = 64 bf16 = 8 granules, swizzled
    __shared__ float red[4 * BM];                //  1 KB

    const int tid  = threadIdx.x;
    const int lane = tid & 63;
    const int w    = tid >> 6;        // wave 0..3
    const int l15  = lane & 15;
    const int quad = lane >> 4;       // 0..3
    const int x7   = l15 & 7;         // swizzle key for fragment reads
    const size_t mbase = (size_t)blockIdx.x * BM;

    f32x4 acc[4][4];
    const f32x4 vzero = {0.0f, 0.0f, 0.0f, 0.0f};
    #pragma unroll
    for (int ii = 0; ii < 4; ++ii)
        #pragma unroll
        for (int jj = 0; jj < 4; ++jj)
            acc[ii][jj] = vzero;

    for (int kc = 0; kc < 8; ++kc){
        __syncthreads();
        // ---- A: 4 chunks/wave, 1 KB each (4 rows x 256 B), fp32 DMA
        {
            const float* Zsrc = (kc < 4) ? sr : si;
            const int kcol = (kc & 3) * 64;
            #pragma unroll
            for (int i = 0; i < 4; ++i){
                const int c  = w*4 + i;                   // chunk 0..15
                const int ar = c*4 + (lane >> 4);         // row 0..63
                const int gg = (lane & 15) ^ (ar & 7);    // swizzled source granule
                const float* gp = Zsrc + (mbase + ar)*DIM + kcol + gg*4;
                gload_lds16(&As[c*256], gp);
            }
        }
        // ---- B: 8 chunks/wave, 1 KB each (8 rows x 128 B), bf16 DMA
        {
            #pragma unroll
            for (int i = 0; i < 8; ++i){
                const int c  = w*8 + i;                   // chunk 0..31
                const int rb = c*8 + (lane >> 3);         // row 0..255
                const int gb = (lane & 7) ^ (rb & 7);
                const unsigned short* gp = G + (size_t)rb*KDIM + kc*64 + gb*8;
                gload_lds16(&Bs[c*512], gp);
            }
        }
        __syncthreads();

        // ---- MFMA: 2 ksteps of 32
        #pragma unroll
        for (int ks = 0; ks < 2; ++ks){
            bf16x8 a[4], b[4];
            const int g0 = ks*8 + quad*2;                 // A granule (4 fp32 each)
            #pragma unroll
            for (int ii = 0; ii < 4; ++ii){
                const int m = ii*16 + l15;
                union { float4 v; uint32_t u[4]; } h0, h1;
                h0.v = *(const float4*)&As[m*64 + ((g0    ) ^ x7)*4];
                h1.v = *(const float4*)&As[m*64 + ((g0 + 1) ^ x7)*4];
                union { uint32_t u[4]; bf16x8 f; } pk;
                pk.u[0] = __builtin_amdgcn_perm(h0.u[1], h0.u[0], 0x07060302);
                pk.u[1] = __builtin_amdgcn_perm(h0.u[3], h0.u[2], 0x07060302);
                pk.u[2] = __builtin_amdgcn_perm(h1.u[1], h1.u[0], 0x07060302);
                pk.u[3] = __builtin_amdgcn_perm(h1.u[3], h1.u[2], 0x07060302);
                a[ii] = pk.f;
            }
            const int gB = ks*4 + quad;                   // B granule (8 bf16 each)
            #pragma unroll
            for (int jj = 0; jj < 4; ++jj){
                const int n = w*64 + jj*16 + l15;
                b[jj] = *(const bf16x8*)&Bs[n*64 + (gB ^ x7)*8];
            }
            #pragma unroll
            for (int ii = 0; ii < 4; ++ii)
                #pragma unroll
                for (int jj = 0; jj < 4; ++jj)
                    acc[ii][jj] = __builtin_amdgcn_mfma_f32_16x16x32_bf16(
                        a[ii], b[jj], acc[ii][jj], 0, 0, 0);
        }
    }

    // ---- epilogue: out[m] = sum_n Y[m][n]^2
    // C/D layout: n = jj*16 + l15, m = ii*16 + quad*4 + r
    float s[4][4];
    #pragma unroll
    for (int ii = 0; ii < 4; ++ii)
        #pragma unroll
        for (int r = 0; r < 4; ++r){
            float t = 0.0f;
            #pragma unroll
            for (int jj = 0; jj < 4; ++jj){ float v = acc[ii][jj][r]; t += v*v; }
            s[ii][r] = t;
        }
    #pragma unroll
    for (int ii = 0; ii < 4; ++ii)
        #pragma unroll
        for (int r = 0; r < 4; ++r){
            float t = s[ii][r];
            t += __shfl_xor(t, 1);
            t += __shfl_xor(t, 2);
            t += __shfl_xor(t, 4);
            t += __shfl_xor(t, 8);
            s[ii][r] = t;
        }
    if (l15 == 0){
        #pragma unroll
        for (int ii = 0; ii < 4; ++ii)
            #pragma unroll
            for (int r = 0; r < 4; ++r)
                red[w*64 + ii*16 + quad*4 + r] = s[ii][r];
    }
    __syncthreads();
    if (tid < 64){
        float o = red[tid] + red[64 + tid] + red[128 + tid] + red[192 + tid];
        out[mbase + tid] = o;
    }
}

extern "C" void kernel_launch(void* const* d_in, const int* in_sizes, int n_in,
                              void* d_out, int out_size, void* d_ws, size_t ws_size,
                              hipStream_t stream){
    const float* params = (const float*)d_in[0];
    const float* sr     = (const float*)d_in[1];
    const float* si     = (const float*)d_in[2];
    unsigned short* G   = (unsigned short*)d_ws;   // 256*512*2 = 256 KB
    float* out          = (float*)d_out;

    build_g_kernel<<<dim3(DIM), dim3(256), 0, stream>>>(params, G);
    qform_kernel<<<dim3(NBLK), dim3(256), 0, stream>>>(sr, si, G, out);
}